// Round 5
// baseline (200.338 us; speedup 1.0000x reference)
//
#include <hip/hip_runtime.h>
#include <hip/hip_bf16.h>

// All float tensors fp32 (proven R1/R2). Output fp32.
// Key algebraic trick (R5): tables store E* = exp(-(logit)) so the edge phase
// computes sigma(a)-sigma(b) = (u-t)/((1+t)(1+u)) with t=ESP*ECS, u=EIP*ECI --
// 1 transcendental (rcp) per channel instead of 4 (2 exp + 2 rcp).
constexpr int EDGES = 250000;
constexpr int EMB   = 64;
constexpr int CNUM  = 128;
constexpr int NSTU  = 10000;
constexpr int NITEM = 50000;
constexpr int NCONC = 2048;

// workspace (fp32): ESP | EIP | ECS | ECI
constexpr size_t ESP_OFF = 0;
constexpr size_t EIP_OFF = ESP_OFF + (size_t)NSTU  * CNUM;
constexpr size_t ECS_OFF = EIP_OFF + (size_t)NITEM * CNUM;
constexpr size_t ECI_OFF = ECS_OFF + (size_t)NCONC * CNUM;

constexpr int TILE = 16;                    // rows staged per block (4 KB LDS)
constexpr int STU_TILES  = NSTU  / TILE;    // 625   (exact)
constexpr int ITEM_TILES = NITEM / TILE;    // 3125  (exact)
constexpr int CONC_TILES = NCONC / TILE;    // 128   (exact)
constexpr int TOTAL_TILES = STU_TILES + ITEM_TILES + CONC_TILES;

constexpr float NEG_LOG2E = -1.44269504088896340736f;

// ---- projection + exp: O[r,c] = exp2(-log2e * dot(F[r,:], W[c, off:off+64]))
// One 16-row tile per block. F staged in LDS (coalesced float4/thread), read
// back via same-address broadcast ds_read_b128 (conflict-free). W row cached
// in 64 VGPRs. No global latency in the inner loop; one barrier per block.
__global__ __launch_bounds__(256) void proj_all(
        const float* __restrict__ stuF, const float* __restrict__ itemF,
        const float* __restrict__ concF,
        const float* __restrict__ W_stu, const float* __restrict__ W_item,
        float* __restrict__ ESP, float* __restrict__ EIP,
        float* __restrict__ ECS, float* __restrict__ ECI) {
    __shared__ float fs[TILE * EMB];
    const int b    = blockIdx.x;
    const int tid  = threadIdx.x;
    const int c    = tid & (CNUM - 1);
    const int half = tid >> 7;   // wave-uniform

    const float* F; const float* W; float* O; int row0, wcol; bool conc;
    if (b < STU_TILES) {
        F = stuF;  W = W_stu;  O = ESP; row0 = b * TILE; wcol = 0; conc = false;
    } else if (b < STU_TILES + ITEM_TILES) {
        F = itemF; W = W_item; O = EIP; row0 = (b - STU_TILES) * TILE; wcol = 0; conc = false;
    } else {
        F = concF; W = half ? W_item : W_stu; O = half ? ECI : ECS;
        row0 = (b - STU_TILES - ITEM_TILES) * TILE; wcol = EMB; conc = true;
    }

    // stage 16 rows = 1024 floats = 256 float4, one per thread, coalesced
    ((float4*)fs)[tid] = ((const float4*)(F + (size_t)row0 * EMB))[tid];

    float w[EMB];
    const float4* Wr = (const float4*)(W + c * (2 * EMB) + wcol);
#pragma unroll
    for (int j = 0; j < 16; ++j) {
        float4 u = Wr[j];
        w[4*j+0] = u.x; w[4*j+1] = u.y; w[4*j+2] = u.z; w[4*j+3] = u.w;
    }
    __syncthreads();

    if (!conc) {
        // halves interleave rows: 8 rows each
#pragma unroll
        for (int i = 0; i < 8; ++i) {
            const int lr = i * 2 + half;
            const float4* fr = (const float4*)(fs + lr * EMB);  // broadcast
            float a0 = 0.f, a1 = 0.f, a2 = 0.f, a3 = 0.f;
#pragma unroll
            for (int j = 0; j < 16; ++j) {
                float4 u = fr[j];
                a0 = fmaf(u.x, w[4*j+0], a0);
                a1 = fmaf(u.y, w[4*j+1], a1);
                a2 = fmaf(u.z, w[4*j+2], a2);
                a3 = fmaf(u.w, w[4*j+3], a3);
            }
            const float d = (a0 + a1) + (a2 + a3);
            O[(size_t)(row0 + lr) * CNUM + c] =
                __builtin_amdgcn_exp2f(d * NEG_LOG2E);
        }
    } else {
        // conc: half 0 -> ECS (W_stu[:,64:]), half 1 -> ECI; each half all 16 rows
#pragma unroll
        for (int lr = 0; lr < TILE; ++lr) {
            const float4* fr = (const float4*)(fs + lr * EMB);
            float a0 = 0.f, a1 = 0.f, a2 = 0.f, a3 = 0.f;
#pragma unroll
            for (int j = 0; j < 16; ++j) {
                float4 u = fr[j];
                a0 = fmaf(u.x, w[4*j+0], a0);
                a1 = fmaf(u.y, w[4*j+1], a1);
                a2 = fmaf(u.z, w[4*j+2], a2);
                a3 = fmaf(u.w, w[4*j+3], a3);
            }
            const float d = (a0 + a1) + (a2 + a3);
            O[(size_t)(row0 + lr) * CNUM + c] =
                __builtin_amdgcn_exp2f(d * NEG_LOG2E);
        }
    }
}

// per-channel contribution: w * (sigma(a) - sigma(b)) with t=e^-a, u=e^-b
// = w * (u - t) / ((1+t)(1+u)).  9 VALU instrs, 1 transcendental.
__device__ __forceinline__ float chan(float es, float ec, float ei, float ecc,
                                      float w) {
    const float t = es * ec;
    const float u = ei * ecc;
    const float den = (1.f + t) * (1.f + u);
    return (w * (u - t)) * __builtin_amdgcn_rcpf(den);
}

__device__ __forceinline__ float sigm(float x) {
    return __builtin_amdgcn_rcpf(
        1.f + __builtin_amdgcn_exp2f(x * NEG_LOG2E));
}

// ---- edge phase: 4 edges/wave, 16 lanes/edge, lane owns 8 channels --------
__global__ __launch_bounds__(256) void edge_kernel(
        const int*  __restrict__ stu_idx,
        const int*  __restrict__ item_idx,
        const int4* __restrict__ conc_idx,
        const float* __restrict__ ESP,
        const float* __restrict__ EIP,
        const float* __restrict__ ECS,
        const float* __restrict__ ECI,
        const float* __restrict__ w_pred,
        const float* __restrict__ b_pred,
        float* __restrict__ out) {
    const int lane = threadIdx.x & 63;
    const int wv   = (blockIdx.x * blockDim.x + threadIdx.x) >> 6;
    const int sub  = lane >> 4;      // edge within wave 0..3
    const int li   = lane & 15;      // lane within edge; owns ch li*8..li*8+7
    const int e    = wv * 4 + sub;   // grid sized exactly

    const int s  = stu_idx[e];
    const int it = item_idx[e];
    const int4 c4 = conc_idx[e];

    const float4* sp4 = (const float4*)(ESP + (size_t)s  * CNUM + li * 8);
    const float4* ip4 = (const float4*)(EIP + (size_t)it * CNUM + li * 8);
    const float4* wp4 = (const float4*)(w_pred + li * 8);
    const float4 esA = sp4[0], esB = sp4[1];
    const float4 eiA = ip4[0], eiB = ip4[1];
    const float4 wA  = wp4[0], wB  = wp4[1];
    const float  b   = b_pred[0];

    const int ck[4] = {c4.x, c4.y, c4.z, c4.w};
    float p[4];
#pragma unroll
    for (int k = 0; k < 4; ++k) {
        const float4* cs4 = (const float4*)(ECS + (size_t)ck[k] * CNUM + li * 8);
        const float4* ci4 = (const float4*)(ECI + (size_t)ck[k] * CNUM + li * 8);
        const float4 csA = cs4[0], csB = cs4[1];
        const float4 ciA = ci4[0], ciB = ci4[1];
        float a0 = 0.f, a1 = 0.f;
        a0 += chan(esA.x, csA.x, eiA.x, ciA.x, wA.x);
        a1 += chan(esA.y, csA.y, eiA.y, ciA.y, wA.y);
        a0 += chan(esA.z, csA.z, eiA.z, ciA.z, wA.z);
        a1 += chan(esA.w, csA.w, eiA.w, ciA.w, wA.w);
        a0 += chan(esB.x, csB.x, eiB.x, ciB.x, wB.x);
        a1 += chan(esB.y, csB.y, eiB.y, ciB.y, wB.y);
        a0 += chan(esB.z, csB.z, eiB.z, ciB.z, wB.z);
        a1 += chan(esB.w, csB.w, eiB.w, ciB.w, wB.w);
        p[k] = a0 + a1;
    }

    // reduce across the 16 lanes of each edge
#pragma unroll
    for (int m = 1; m <= 8; m <<= 1) {
        p[0] += __shfl_xor(p[0], m, 64);
        p[1] += __shfl_xor(p[1], m, 64);
        p[2] += __shfl_xor(p[2], m, 64);
        p[3] += __shfl_xor(p[3], m, 64);
    }

    const float r = 0.25f * (sigm(p[0] + b) + sigm(p[1] + b) +
                             sigm(p[2] + b) + sigm(p[3] + b));
    if (li == 0) out[e] = r;
}

extern "C" void kernel_launch(void* const* d_in, const int* in_sizes, int n_in,
                              void* d_out, int out_size, void* d_ws, size_t ws_size,
                              hipStream_t stream) {
    const int* stu_idx  = (const int*)d_in[0];
    const int* item_idx = (const int*)d_in[1];
    const int* conc_idx = (const int*)d_in[2];
    const float* stu_fusion     = (const float*)d_in[3];
    const float* item_fusion    = (const float*)d_in[4];
    const float* concept_fusion = (const float*)d_in[5];
    const float* W_stu          = (const float*)d_in[6];
    const float* W_item         = (const float*)d_in[7];
    const float* w_pred         = (const float*)d_in[8];
    const float* b_pred         = (const float*)d_in[9];
    float* out = (float*)d_out;

    float* ESP = (float*)d_ws + ESP_OFF;
    float* EIP = (float*)d_ws + EIP_OFF;
    float* ECS = (float*)d_ws + ECS_OFF;
    float* ECI = (float*)d_ws + ECI_OFF;

    proj_all<<<TOTAL_TILES, 256, 0, stream>>>(
        stu_fusion, item_fusion, concept_fusion, W_stu, W_item,
        ESP, EIP, ECS, ECI);

    edge_kernel<<<EDGES / 16, 256, 0, stream>>>(
        stu_idx, item_idx, (const int4*)conc_idx,
        ESP, EIP, ECS, ECI, w_pred, b_pred, out);
}

// Round 6
// 150.757 us; speedup vs baseline: 1.3289x; 1.3289x over previous
//
#include <hip/hip_runtime.h>
#include <hip/hip_bf16.h>
#include <hip/hip_fp16.h>

// All float tensors fp32 (proven R1/R2). Output fp32.
// Tables store E* = exp(-logit) in FP16 (halves gather traffic; rel err 2.4e-4,
// output impact ~1e-4 vs threshold 1.96e-2). Edge computes
// sigma(a)-sigma(b) = (u-t)/((1+t)(1+u)), t=ESP*ECS, u=EIP*ECI: 1 rcp/channel.
constexpr int EDGES = 250000;
constexpr int EMB   = 64;
constexpr int CNUM  = 128;
constexpr int NSTU  = 10000;
constexpr int NITEM = 50000;
constexpr int NCONC = 2048;

// workspace (fp16 halves): ESP | EIP | ECS | ECI
constexpr size_t ESP_OFF = 0;
constexpr size_t EIP_OFF = ESP_OFF + (size_t)NSTU  * CNUM;
constexpr size_t ECS_OFF = EIP_OFF + (size_t)NITEM * CNUM;
constexpr size_t ECI_OFF = ECS_OFF + (size_t)NCONC * CNUM;

constexpr int TILE = 16;                       // rows per proj block (4 KB LDS)
constexpr int STU_TILES   = NSTU  / TILE;      // 625  (exact)
constexpr int ITEM_TILES  = NITEM / TILE;      // 3125 (exact)
constexpr int CONC_GROUPS = (NCONC / TILE)*2;  // 128 tiles x {ECS, ECI}
constexpr int TOTAL_BLKS  = STU_TILES + ITEM_TILES + CONC_GROUPS;

constexpr float NEG_LOG2E = -1.44269504088896340736f;

// ---- projection + exp -> fp16 tables --------------------------------------
// Per block: 16 rows staged in LDS. Wave wv owns channels wv*32..wv*32+31;
// lane's kh = lane>>5 picks which half of K it accumulates (w cache = 32 VGPR,
// not 64). Partials merged with one shfl_xor(32) — no barrier, no LDS reduce.
__global__ __launch_bounds__(256) void proj_all(
        const float* __restrict__ stuF, const float* __restrict__ itemF,
        const float* __restrict__ concF,
        const float* __restrict__ W_stu, const float* __restrict__ W_item,
        __half* __restrict__ ESP, __half* __restrict__ EIP,
        __half* __restrict__ ECS, __half* __restrict__ ECI) {
    __shared__ float fs[TILE * EMB];
    const int b    = blockIdx.x;
    const int tid  = threadIdx.x;
    const int wv   = tid >> 6;
    const int lane = tid & 63;
    const int cl   = lane & 31;   // channel within wave slice
    const int kh   = lane >> 5;   // which K-half this lane accumulates
    const int c    = wv * 32 + cl;

    const float* F; const float* W; __half* O; int row0, wcol;
    if (b < STU_TILES) {
        F = stuF;  W = W_stu;  O = ESP; row0 = b * TILE; wcol = 0;
    } else if (b < STU_TILES + ITEM_TILES) {
        F = itemF; W = W_item; O = EIP; row0 = (b - STU_TILES) * TILE; wcol = 0;
    } else {
        const int g = b - STU_TILES - ITEM_TILES;
        F = concF; W = (g & 1) ? W_item : W_stu; O = (g & 1) ? ECI : ECS;
        row0 = (g >> 1) * TILE; wcol = EMB;
    }

    // stage 16 rows = 1024 floats = 256 float4, one per thread, coalesced
    ((float4*)fs)[tid] = ((const float4*)(F + (size_t)row0 * EMB))[tid];

    float w[32];
    const float4* Wr = (const float4*)(W + c * (2 * EMB) + wcol + kh * 32);
#pragma unroll
    for (int j = 0; j < 8; ++j) {
        float4 u = Wr[j];
        w[4*j+0] = u.x; w[4*j+1] = u.y; w[4*j+2] = u.z; w[4*j+3] = u.w;
    }
    __syncthreads();

#pragma unroll
    for (int r = 0; r < TILE; ++r) {
        // half-wave broadcast reads (2 distinct addrs per wave: conflict-free)
        const float4* fr = (const float4*)(fs + r * EMB + kh * 32);
        float a0 = 0.f, a1 = 0.f, a2 = 0.f, a3 = 0.f;
#pragma unroll
        for (int j = 0; j < 8; ++j) {
            float4 u = fr[j];
            a0 = fmaf(u.x, w[4*j+0], a0);
            a1 = fmaf(u.y, w[4*j+1], a1);
            a2 = fmaf(u.z, w[4*j+2], a2);
            a3 = fmaf(u.w, w[4*j+3], a3);
        }
        float d = (a0 + a1) + (a2 + a3);
        d += __shfl_xor(d, 32, 64);              // merge the two K-halves
        const float e = __builtin_amdgcn_exp2f(d * NEG_LOG2E);
        if (kh == 0) O[(size_t)(row0 + r) * CNUM + c] = __float2half(e);
    }
}

// unpack 8 fp16 (one dwordx4) to fp32
__device__ __forceinline__ void h8f(const uint4 u, float* f) {
    const __half2* h = (const __half2*)&u;
#pragma unroll
    for (int i = 0; i < 4; ++i) {
        float2 v = __half22float2(h[i]);
        f[2*i] = v.x; f[2*i+1] = v.y;
    }
}

// w * (sigma(a)-sigma(b)) from t=e^-a, u=e^-b: 1 transcendental
__device__ __forceinline__ float chan(float es, float ec, float ei, float ecc,
                                      float w) {
    const float t = es * ec;
    const float u = ei * ecc;
    return (w * (u - t)) * __builtin_amdgcn_rcpf((1.f + t) * (1.f + u));
}

__device__ __forceinline__ float sigm(float x) {
    return __builtin_amdgcn_rcpf(1.f + __builtin_amdgcn_exp2f(x * NEG_LOG2E));
}

// ---- edge phase: 4 edges/wave, 16 lanes/edge, lane owns 8 channels --------
__global__ __launch_bounds__(256) void edge_kernel(
        const int*  __restrict__ stu_idx,
        const int*  __restrict__ item_idx,
        const int4* __restrict__ conc_idx,
        const __half* __restrict__ ESP,
        const __half* __restrict__ EIP,
        const __half* __restrict__ ECS,
        const __half* __restrict__ ECI,
        const float* __restrict__ w_pred,
        const float* __restrict__ b_pred,
        float* __restrict__ out) {
    const int lane = threadIdx.x & 63;
    const int wvg  = (blockIdx.x * blockDim.x + threadIdx.x) >> 6;
    const int sub  = lane >> 4;      // edge within wave 0..3
    const int li   = lane & 15;      // lane within edge; owns ch li*8..li*8+7
    const int e    = wvg * 4 + sub;  // grid sized exactly

    const int s  = stu_idx[e];
    const int it = item_idx[e];
    const int4 c4 = conc_idx[e];

    float es[8], ei[8], wf[8];
    h8f(*(const uint4*)(ESP + (size_t)s  * CNUM + li * 8), es);
    h8f(*(const uint4*)(EIP + (size_t)it * CNUM + li * 8), ei);
    {
        const float4* wp4 = (const float4*)(w_pred + li * 8);
        float4 a = wp4[0], b4 = wp4[1];
        wf[0]=a.x; wf[1]=a.y; wf[2]=a.z; wf[3]=a.w;
        wf[4]=b4.x; wf[5]=b4.y; wf[6]=b4.z; wf[7]=b4.w;
    }
    const float b = b_pred[0];

    const int ck[4] = {c4.x, c4.y, c4.z, c4.w};
    float p[4];
#pragma unroll
    for (int k = 0; k < 4; ++k) {
        float cs[8], ci[8];
        h8f(*(const uint4*)(ECS + (size_t)ck[k] * CNUM + li * 8), cs);
        h8f(*(const uint4*)(ECI + (size_t)ck[k] * CNUM + li * 8), ci);
        float a0 = 0.f, a1 = 0.f;
#pragma unroll
        for (int j = 0; j < 8; j += 2) {
            a0 += chan(es[j],   cs[j],   ei[j],   ci[j],   wf[j]);
            a1 += chan(es[j+1], cs[j+1], ei[j+1], ci[j+1], wf[j+1]);
        }
        p[k] = a0 + a1;
    }

    // reduce across the 16 lanes of each edge
#pragma unroll
    for (int m = 1; m <= 8; m <<= 1) {
        p[0] += __shfl_xor(p[0], m, 64);
        p[1] += __shfl_xor(p[1], m, 64);
        p[2] += __shfl_xor(p[2], m, 64);
        p[3] += __shfl_xor(p[3], m, 64);
    }

    const float r = 0.25f * (sigm(p[0] + b) + sigm(p[1] + b) +
                             sigm(p[2] + b) + sigm(p[3] + b));
    if (li == 0) out[e] = r;
}

extern "C" void kernel_launch(void* const* d_in, const int* in_sizes, int n_in,
                              void* d_out, int out_size, void* d_ws, size_t ws_size,
                              hipStream_t stream) {
    const int* stu_idx  = (const int*)d_in[0];
    const int* item_idx = (const int*)d_in[1];
    const int* conc_idx = (const int*)d_in[2];
    const float* stu_fusion     = (const float*)d_in[3];
    const float* item_fusion    = (const float*)d_in[4];
    const float* concept_fusion = (const float*)d_in[5];
    const float* W_stu          = (const float*)d_in[6];
    const float* W_item         = (const float*)d_in[7];
    const float* w_pred         = (const float*)d_in[8];
    const float* b_pred         = (const float*)d_in[9];
    float* out = (float*)d_out;

    __half* ESP = (__half*)d_ws + ESP_OFF;
    __half* EIP = (__half*)d_ws + EIP_OFF;
    __half* ECS = (__half*)d_ws + ECS_OFF;
    __half* ECI = (__half*)d_ws + ECI_OFF;

    proj_all<<<TOTAL_BLKS, 256, 0, stream>>>(
        stu_fusion, item_fusion, concept_fusion, W_stu, W_item,
        ESP, EIP, ECS, ECI);

    edge_kernel<<<EDGES / 16, 256, 0, stream>>>(
        stu_idx, item_idx, (const int4*)conc_idx,
        ESP, EIP, ECS, ECI, w_pred, b_pred, out);
}

// Round 7
// 145.243 us; speedup vs baseline: 1.3793x; 1.0380x over previous
//
#include <hip/hip_runtime.h>
#include <hip/hip_bf16.h>
#include <hip/hip_fp16.h>

// All float tensors fp32 (proven R1/R2). Output fp32.
// Tables store E* = exp(-logit) in FP16. Edge computes
// sigma(a)-sigma(b) = (u-t)/((1+t)(1+u)), t=ESP*ECS, u=EIP*ECI: 1 rcp/channel.
// R7: projection via MFMA (f32->f16 inputs, fp32 accum) — the projection is 3
// small GEMMs (64096x128x64); broadcast-based VALU schemes (R3 VMEM, R4 SMEM,
// R6 LDS) all paid ~4x the FMA work in per-instruction broadcast costs.
constexpr int EDGES = 250000;
constexpr int EMB   = 64;
constexpr int CNUM  = 128;
constexpr int NSTU  = 10000;
constexpr int NITEM = 50000;
constexpr int NCONC = 2048;

// workspace (fp16 halves): ESP | EIP | ECS | ECI
constexpr size_t ESP_OFF = 0;
constexpr size_t EIP_OFF = ESP_OFF + (size_t)NSTU  * CNUM;
constexpr size_t ECS_OFF = EIP_OFF + (size_t)NITEM * CNUM;
constexpr size_t ECI_OFF = ECS_OFF + (size_t)NCONC * CNUM;

constexpr float NEG_LOG2E = -1.44269504088896340736f;

// proj job space: one wave per 16-row strip (conc strips: one wave per table)
constexpr int STU_JOBS  = NSTU  / 16;            // 625
constexpr int ITEM_JOBS = NITEM / 16;            // 3125
constexpr int CONC_JOBS = (NCONC / 16) * 2;      // 256  (x{ECS,ECI})
constexpr int NJOBS     = STU_JOBS + ITEM_JOBS + CONC_JOBS;  // 4006
constexpr int PROJ_BLKS = (NJOBS + 3) / 4;       // 4 waves per 256-block

typedef _Float16 half8 __attribute__((ext_vector_type(8)));
typedef float    f32x4 __attribute__((ext_vector_type(4)));

__device__ __forceinline__ half8 pack8(float4 lo, float4 hi) {
    half8 h;
    h[0] = (_Float16)lo.x; h[1] = (_Float16)lo.y;
    h[2] = (_Float16)lo.z; h[3] = (_Float16)lo.w;
    h[4] = (_Float16)hi.x; h[5] = (_Float16)hi.y;
    h[6] = (_Float16)hi.z; h[7] = (_Float16)hi.w;
    return h;
}

// ---- projection via MFMA: O[r,c] = exp(-dot(F[r,:], W[c, wcol:wcol+64])) ---
// Wave-level 16x16x32 f16 MFMA. A-frag: lane holds F[strip*16 + (lane&15)]
// [q*8+j] (q=lane>>4). B-frag mirrors A from W rows (out = F * W2^T). C/D:
// row = q*4+reg, col = lane&15. K=64 -> 2 MFMAs per 16x16 tile; wave loops
// the 8 channel-tiles (W is L1/L2-hot: 128 KB total).
__global__ __launch_bounds__(256) void proj_mfma(
        const float* __restrict__ stuF, const float* __restrict__ itemF,
        const float* __restrict__ concF,
        const float* __restrict__ W_stu, const float* __restrict__ W_item,
        __half* __restrict__ ESP, __half* __restrict__ EIP,
        __half* __restrict__ ECS, __half* __restrict__ ECI) {
    const int tid  = threadIdx.x;
    const int lane = tid & 63;
    const int job  = blockIdx.x * 4 + (tid >> 6);
    if (job >= NJOBS) return;

    const float* F; const float* W; __half* O; int strip, wcol;
    if (job < STU_JOBS) {
        F = stuF;  W = W_stu;  O = ESP; strip = job; wcol = 0;
    } else if (job < STU_JOBS + ITEM_JOBS) {
        F = itemF; W = W_item; O = EIP; strip = job - STU_JOBS; wcol = 0;
    } else {
        const int g = job - STU_JOBS - ITEM_JOBS;
        F = concF; W = (g & 1) ? W_item : W_stu; O = (g & 1) ? ECI : ECS;
        strip = g >> 1; wcol = EMB;
    }

    const int m = lane & 15;       // A row / B channel / D col
    const int q = lane >> 4;       // quad
    const int row = strip * 16 + m;

    // A fragments (K 0..31 and 32..63), cast f32 -> f16
    const float4* fa = (const float4*)(F + (size_t)row * EMB + q * 8);
    const float4* fb = (const float4*)(F + (size_t)row * EMB + 32 + q * 8);
    const half8 A0 = pack8(fa[0], fa[1]);
    const half8 A1 = pack8(fb[0], fb[1]);

    const int orow = strip * 16 + q * 4;   // D rows q*4..q*4+3

#pragma unroll
    for (int ct = 0; ct < 8; ++ct) {
        const int ch = ct * 16 + m;
        const float* wr = W + (size_t)ch * (2 * EMB) + wcol;
        const float4* wb0 = (const float4*)(wr + q * 8);
        const float4* wb1 = (const float4*)(wr + 32 + q * 8);
        const half8 B0 = pack8(wb0[0], wb0[1]);
        const half8 B1 = pack8(wb1[0], wb1[1]);

        f32x4 acc = {0.f, 0.f, 0.f, 0.f};
        acc = __builtin_amdgcn_mfma_f32_16x16x32_f16(A0, B0, acc, 0, 0, 0);
        acc = __builtin_amdgcn_mfma_f32_16x16x32_f16(A1, B1, acc, 0, 0, 0);

#pragma unroll
        for (int r = 0; r < 4; ++r) {
            const float e = __builtin_amdgcn_exp2f(acc[r] * NEG_LOG2E);
            O[(size_t)(orow + r) * CNUM + ct * 16 + m] = __float2half(e);
        }
    }
}

// unpack 8 fp16 (one dwordx4) to fp32
__device__ __forceinline__ void h8f(const uint4 u, float* f) {
    const __half2* h = (const __half2*)&u;
#pragma unroll
    for (int i = 0; i < 4; ++i) {
        float2 v = __half22float2(h[i]);
        f[2*i] = v.x; f[2*i+1] = v.y;
    }
}

// w * (sigma(a)-sigma(b)) from t=e^-a, u=e^-b: 1 transcendental
__device__ __forceinline__ float chan(float es, float ec, float ei, float ecc,
                                      float w) {
    const float t = es * ec;
    const float u = ei * ecc;
    return (w * (u - t)) * __builtin_amdgcn_rcpf((1.f + t) * (1.f + u));
}

__device__ __forceinline__ float sigm(float x) {
    return __builtin_amdgcn_rcpf(1.f + __builtin_amdgcn_exp2f(x * NEG_LOG2E));
}

// ---- edge phase: 4 edges/wave, 16 lanes/edge, lane owns 8 channels --------
__global__ __launch_bounds__(256) void edge_kernel(
        const int*  __restrict__ stu_idx,
        const int*  __restrict__ item_idx,
        const int4* __restrict__ conc_idx,
        const __half* __restrict__ ESP,
        const __half* __restrict__ EIP,
        const __half* __restrict__ ECS,
        const __half* __restrict__ ECI,
        const float* __restrict__ w_pred,
        const float* __restrict__ b_pred,
        float* __restrict__ out) {
    const int lane = threadIdx.x & 63;
    const int wvg  = (blockIdx.x * blockDim.x + threadIdx.x) >> 6;
    const int sub  = lane >> 4;      // edge within wave 0..3
    const int li   = lane & 15;      // lane within edge; owns ch li*8..li*8+7
    const int e    = wvg * 4 + sub;  // grid sized exactly

    const int s  = stu_idx[e];
    const int it = item_idx[e];
    const int4 c4 = conc_idx[e];

    float es[8], ei[8], wf[8];
    h8f(*(const uint4*)(ESP + (size_t)s  * CNUM + li * 8), es);
    h8f(*(const uint4*)(EIP + (size_t)it * CNUM + li * 8), ei);
    {
        const float4* wp4 = (const float4*)(w_pred + li * 8);
        float4 a = wp4[0], b4 = wp4[1];
        wf[0]=a.x; wf[1]=a.y; wf[2]=a.z; wf[3]=a.w;
        wf[4]=b4.x; wf[5]=b4.y; wf[6]=b4.z; wf[7]=b4.w;
    }
    const float b = b_pred[0];

    const int ck[4] = {c4.x, c4.y, c4.z, c4.w};
    float p[4];
#pragma unroll
    for (int k = 0; k < 4; ++k) {
        float cs[8], ci[8];
        h8f(*(const uint4*)(ECS + (size_t)ck[k] * CNUM + li * 8), cs);
        h8f(*(const uint4*)(ECI + (size_t)ck[k] * CNUM + li * 8), ci);
        float a0 = 0.f, a1 = 0.f;
#pragma unroll
        for (int j = 0; j < 8; j += 2) {
            a0 += chan(es[j],   cs[j],   ei[j],   ci[j],   wf[j]);
            a1 += chan(es[j+1], cs[j+1], ei[j+1], ci[j+1], wf[j+1]);
        }
        p[k] = a0 + a1;
    }

    // reduce across the 16 lanes of each edge
#pragma unroll
    for (int m = 1; m <= 8; m <<= 1) {
        p[0] += __shfl_xor(p[0], m, 64);
        p[1] += __shfl_xor(p[1], m, 64);
        p[2] += __shfl_xor(p[2], m, 64);
        p[3] += __shfl_xor(p[3], m, 64);
    }

    const float r = 0.25f * (sigm(p[0] + b) + sigm(p[1] + b) +
                             sigm(p[2] + b) + sigm(p[3] + b));
    if (li == 0) out[e] = r;
}

extern "C" void kernel_launch(void* const* d_in, const int* in_sizes, int n_in,
                              void* d_out, int out_size, void* d_ws, size_t ws_size,
                              hipStream_t stream) {
    const int* stu_idx  = (const int*)d_in[0];
    const int* item_idx = (const int*)d_in[1];
    const int* conc_idx = (const int*)d_in[2];
    const float* stu_fusion     = (const float*)d_in[3];
    const float* item_fusion    = (const float*)d_in[4];
    const float* concept_fusion = (const float*)d_in[5];
    const float* W_stu          = (const float*)d_in[6];
    const float* W_item         = (const float*)d_in[7];
    const float* w_pred         = (const float*)d_in[8];
    const float* b_pred         = (const float*)d_in[9];
    float* out = (float*)d_out;

    __half* ESP = (__half*)d_ws + ESP_OFF;
    __half* EIP = (__half*)d_ws + EIP_OFF;
    __half* ECS = (__half*)d_ws + ECS_OFF;
    __half* ECI = (__half*)d_ws + ECI_OFF;

    proj_mfma<<<PROJ_BLKS, 256, 0, stream>>>(
        stu_fusion, item_fusion, concept_fusion, W_stu, W_item,
        ESP, EIP, ECS, ECI);

    edge_kernel<<<EDGES / 16, 256, 0, stream>>>(
        stu_idx, item_idx, (const int4*)conc_idx,
        ESP, EIP, ECS, ECI, w_pred, b_pred, out);
}

// Round 8
// 136.184 us; speedup vs baseline: 1.4711x; 1.0665x over previous
//
#include <hip/hip_runtime.h>
#include <hip/hip_bf16.h>
#include <hip/hip_fp16.h>

// All float tensors fp32 (proven R1/R2). Output fp32.
// Tables store E* = exp(-logit) in FP16; edge computes
// sigma(a)-sigma(b) = (u-t)/((1+t)(1+u)) with t=ESP*ECS, u=EIP*ECI entirely in
// PACKED fp16 (v_pk_*), 1 v_rcp_f16 per channel, zero unpack cvts.
// Reduction via DPP butterfly (xor-basis {1,2,7,15}) — no LDS pipe.
constexpr int EDGES = 250000;
constexpr int EMB   = 64;
constexpr int CNUM  = 128;
constexpr int NSTU  = 10000;
constexpr int NITEM = 50000;
constexpr int NCONC = 2048;

// workspace (_Float16): ESP | EIP | ECS | ECI | WH(w_pred fp16, 128)
constexpr size_t ESP_OFF = 0;
constexpr size_t EIP_OFF = ESP_OFF + (size_t)NSTU  * CNUM;
constexpr size_t ECS_OFF = EIP_OFF + (size_t)NITEM * CNUM;
constexpr size_t ECI_OFF = ECS_OFF + (size_t)NCONC * CNUM;
constexpr size_t WH_OFF  = ECI_OFF + (size_t)NCONC * CNUM;

constexpr float NEG_LOG2E = -1.44269504088896340736f;

// proj job space: one wave per 16-row strip (conc strips: one wave per table)
constexpr int STU_JOBS  = NSTU  / 16;            // 625
constexpr int ITEM_JOBS = NITEM / 16;            // 3125
constexpr int CONC_JOBS = (NCONC / 16) * 2;      // 256
constexpr int NJOBS     = STU_JOBS + ITEM_JOBS + CONC_JOBS;  // 4006
constexpr int PROJ_BLKS = (NJOBS + 3) / 4;

typedef _Float16 h8 __attribute__((ext_vector_type(8)));
typedef _Float16 h4 __attribute__((ext_vector_type(4)));
typedef _Float16 h2 __attribute__((ext_vector_type(2)));
typedef float    f32x4 __attribute__((ext_vector_type(4)));

__device__ __forceinline__ h8 pack8(float4 lo, float4 hi) {
    h8 h;
    h[0] = (_Float16)lo.x; h[1] = (_Float16)lo.y;
    h[2] = (_Float16)lo.z; h[3] = (_Float16)lo.w;
    h[4] = (_Float16)hi.x; h[5] = (_Float16)hi.y;
    h[6] = (_Float16)hi.z; h[7] = (_Float16)hi.w;
    return h;
}

__device__ __forceinline__ _Float16 rcp16(_Float16 x) {
#if __has_builtin(__builtin_amdgcn_rcph)
    return __builtin_amdgcn_rcph(x);
#else
    return (_Float16)__builtin_amdgcn_rcpf((float)x);
#endif
}

// x += dpp-permuted x (full-rate VALU, no LDS pipe)
template <int CTRL>
__device__ __forceinline__ float dppadd(float x) {
    return x + __int_as_float(__builtin_amdgcn_update_dpp(
        0, __float_as_int(x), CTRL, 0xf, 0xf, true));
}

// ---- projection via MFMA: O[r,c] = exp(-dot(F[r,:], W[c, wcol:wcol+64])) ---
__global__ __launch_bounds__(256) void proj_mfma(
        const float* __restrict__ stuF, const float* __restrict__ itemF,
        const float* __restrict__ concF,
        const float* __restrict__ W_stu, const float* __restrict__ W_item,
        const float* __restrict__ w_pred,
        _Float16* __restrict__ ESP, _Float16* __restrict__ EIP,
        _Float16* __restrict__ ECS, _Float16* __restrict__ ECI,
        _Float16* __restrict__ WH) {
    const int tid  = threadIdx.x;
    const int lane = tid & 63;
    const int job  = blockIdx.x * 4 + (tid >> 6);
    if (job >= NJOBS) return;

    if (job == 0) {  // one wave converts w_pred (128 f32) to fp16 once
        const float2 wv2 = ((const float2*)w_pred)[lane];
        h2 wh; wh[0] = (_Float16)wv2.x; wh[1] = (_Float16)wv2.y;
        *(h2*)(WH + 2 * lane) = wh;
    }

    const float* F; const float* W; _Float16* O; int strip, wcol;
    if (job < STU_JOBS) {
        F = stuF;  W = W_stu;  O = ESP; strip = job; wcol = 0;
    } else if (job < STU_JOBS + ITEM_JOBS) {
        F = itemF; W = W_item; O = EIP; strip = job - STU_JOBS; wcol = 0;
    } else {
        const int g = job - STU_JOBS - ITEM_JOBS;
        F = concF; W = (g & 1) ? W_item : W_stu; O = (g & 1) ? ECI : ECS;
        strip = g >> 1; wcol = EMB;
    }

    const int m = lane & 15;       // A row / B channel / D col
    const int q = lane >> 4;       // quad
    const int row = strip * 16 + m;

    const float4* fa = (const float4*)(F + (size_t)row * EMB + q * 8);
    const float4* fb = (const float4*)(F + (size_t)row * EMB + 32 + q * 8);
    const h8 A0 = pack8(fa[0], fa[1]);
    const h8 A1 = pack8(fb[0], fb[1]);

    const int orow = strip * 16 + q * 4;

#pragma unroll
    for (int ct = 0; ct < 8; ++ct) {
        const int ch = ct * 16 + m;
        const float* wr = W + (size_t)ch * (2 * EMB) + wcol;
        const float4* wb0 = (const float4*)(wr + q * 8);
        const float4* wb1 = (const float4*)(wr + 32 + q * 8);
        const h8 B0 = pack8(wb0[0], wb0[1]);
        const h8 B1 = pack8(wb1[0], wb1[1]);

        f32x4 acc = {0.f, 0.f, 0.f, 0.f};
        acc = __builtin_amdgcn_mfma_f32_16x16x32_f16(A0, B0, acc, 0, 0, 0);
        acc = __builtin_amdgcn_mfma_f32_16x16x32_f16(A1, B1, acc, 0, 0, 0);

#pragma unroll
        for (int r = 0; r < 4; ++r) {
            const float e = __builtin_amdgcn_exp2f(acc[r] * NEG_LOG2E);
            O[(size_t)(orow + r) * CNUM + ct * 16 + m] = (_Float16)e;
        }
    }
}

__device__ __forceinline__ float sigm(float x) {
    return __builtin_amdgcn_rcpf(1.f + __builtin_amdgcn_exp2f(x * NEG_LOG2E));
}

// ---- edge phase: 4 edges/wave, 16 lanes/edge, lane owns 8 channels --------
__global__ __launch_bounds__(256) void edge_kernel(
        const int*  __restrict__ stu_idx,
        const int*  __restrict__ item_idx,
        const int4* __restrict__ conc_idx,
        const _Float16* __restrict__ ESP,
        const _Float16* __restrict__ EIP,
        const _Float16* __restrict__ ECS,
        const _Float16* __restrict__ ECI,
        const _Float16* __restrict__ WH,
        const float* __restrict__ b_pred,
        float* __restrict__ out) {
    const int lane = threadIdx.x & 63;
    const int wvg  = (blockIdx.x * blockDim.x + threadIdx.x) >> 6;
    const int sub  = lane >> 4;      // edge within wave 0..3
    const int li   = lane & 15;      // lane within edge; owns ch li*8..li*8+7
    const int e    = wvg * 4 + sub;  // grid sized exactly

    const int s  = stu_idx[e];
    const int it = item_idx[e];
    const int4 c4 = conc_idx[e];

    const h8 es = *(const h8*)(ESP + (size_t)s  * CNUM + li * 8);
    const h8 ei = *(const h8*)(EIP + (size_t)it * CNUM + li * 8);
    const h8 w8 = *(const h8*)(WH + li * 8);
    const float b = b_pred[0];

    const h8 ONE = {(_Float16)1, (_Float16)1, (_Float16)1, (_Float16)1,
                    (_Float16)1, (_Float16)1, (_Float16)1, (_Float16)1};

    const int ck[4] = {c4.x, c4.y, c4.z, c4.w};
    float p[4];
#pragma unroll
    for (int k = 0; k < 4; ++k) {
        const h8 cs = *(const h8*)(ECS + (size_t)ck[k] * CNUM + li * 8);
        const h8 ci = *(const h8*)(ECI + (size_t)ck[k] * CNUM + li * 8);
        const h8 t   = es * cs;              // e^-(sp+cs)   (v_pk_mul)
        const h8 u   = ei * ci;              // e^-(ip+ci)
        const h8 den = (t + ONE) * (u + ONE);
        const h8 num = w8 * (u - t);
        h8 r;
#pragma unroll
        for (int i = 0; i < 8; ++i) r[i] = num[i] * rcp16(den[i]);
        const h4 q4 = __builtin_shufflevector(r, r, 0, 1, 2, 3)
                    + __builtin_shufflevector(r, r, 4, 5, 6, 7);
        const h2 q2 = __builtin_shufflevector(q4, q4, 0, 1)
                    + __builtin_shufflevector(q4, q4, 2, 3);
        p[k] = (float)q2[0] + (float)q2[1];
    }

    // 16-lane sum via DPP butterfly; xor-basis {1,2,7,15} spans the group.
#pragma unroll
    for (int j = 0; j < 4; ++j) p[j] = dppadd<0xB1>(p[j]);   // quad_perm xor1
#pragma unroll
    for (int j = 0; j < 4; ++j) p[j] = dppadd<0x4E>(p[j]);   // quad_perm xor2
#pragma unroll
    for (int j = 0; j < 4; ++j) p[j] = dppadd<0x141>(p[j]);  // row_half_mirror
#pragma unroll
    for (int j = 0; j < 4; ++j) p[j] = dppadd<0x140>(p[j]);  // row_mirror

    const float r = 0.25f * (sigm(p[0] + b) + sigm(p[1] + b) +
                             sigm(p[2] + b) + sigm(p[3] + b));
    if (li == 0) out[e] = r;
}

extern "C" void kernel_launch(void* const* d_in, const int* in_sizes, int n_in,
                              void* d_out, int out_size, void* d_ws, size_t ws_size,
                              hipStream_t stream) {
    const int* stu_idx  = (const int*)d_in[0];
    const int* item_idx = (const int*)d_in[1];
    const int* conc_idx = (const int*)d_in[2];
    const float* stu_fusion     = (const float*)d_in[3];
    const float* item_fusion    = (const float*)d_in[4];
    const float* concept_fusion = (const float*)d_in[5];
    const float* W_stu          = (const float*)d_in[6];
    const float* W_item         = (const float*)d_in[7];
    const float* w_pred         = (const float*)d_in[8];
    const float* b_pred         = (const float*)d_in[9];
    float* out = (float*)d_out;

    _Float16* ESP = (_Float16*)d_ws + ESP_OFF;
    _Float16* EIP = (_Float16*)d_ws + EIP_OFF;
    _Float16* ECS = (_Float16*)d_ws + ECS_OFF;
    _Float16* ECI = (_Float16*)d_ws + ECI_OFF;
    _Float16* WH  = (_Float16*)d_ws + WH_OFF;

    proj_mfma<<<PROJ_BLKS, 256, 0, stream>>>(
        stu_fusion, item_fusion, concept_fusion, W_stu, W_item, w_pred,
        ESP, EIP, ECS, ECI, WH);

    edge_kernel<<<EDGES / 16, 256, 0, stream>>>(
        stu_idx, item_idx, (const int4*)conc_idx,
        ESP, EIP, ECS, ECI, WH, b_pred, out);
}